// Round 2
// baseline (720.549 us; speedup 1.0000x reference)
//
#include <hip/hip_runtime.h>
#include <hip/hip_bf16.h>

// SDPA with materialized attention weights. B=2,H=16,S=2048,D=64, fp32 in/out.
// Outputs: O [B,H,S,D] then attn_weights [B,H,S,S] concatenated in d_out.
// Causal mask is structural (tril) -> k<=q, mask input unread.
//
// Round3 (resubmit; Round-1 bench was an infra failure, not a kernel failure):
// barrier-free main kernel. K/V per XCD is only 2MB -> L2-resident, so
// LDS staging + __syncthreads (2-3 per k-tile, vmcnt(0) drains) was pure
// latency overhead. All MFMA fragments (Q,K,V^T) are 16B-contiguous in the
// bf16 ws buffers -> load straight from global/L2 into registers. Only the
// wave-private P transpose buffer stays in LDS (no barriers at all).
// K-frags double-buffered in registers; V-frags issued a softmax-phase early.
// Balanced qb mapping: each CU's 4 blocks sum to exactly 66 ktiles.
// Non-temporal stores for P / zero-fill keep L2 for K/V.

#define S_ 2048
#define D_ 64
#define BH_ 32

typedef short short8 __attribute__((ext_vector_type(8)));
typedef float f32x4 __attribute__((ext_vector_type(4)));
typedef unsigned short ushort4v __attribute__((ext_vector_type(4)));

__device__ __forceinline__ unsigned short f2bf(float f) {
  union { float f; unsigned u; } c; c.f = f;
  unsigned u = c.u + 0x7fffu + ((c.u >> 16) & 1u);  // RNE
  return (unsigned short)(u >> 16);
}

// ---------------- pre-kernels ----------------
__global__ __launch_bounds__(256) void cvt_bf16(const float* __restrict__ src,
                                                unsigned short* __restrict__ dst, int n4) {
  int i = blockIdx.x * 256 + threadIdx.x;
  if (i < n4) {
    float4 v = ((const float4*)src)[i];
    ushort4v u = { f2bf(v.x), f2bf(v.y), f2bf(v.z), f2bf(v.w) };
    ((ushort4v*)dst)[i] = u;
  }
}

// V [bh][s][d] fp32 -> Vt [bh][d][s] bf16
__global__ __launch_bounds__(256) void vtrans(const float* __restrict__ V,
                                              unsigned short* __restrict__ Vt) {
  __shared__ float T[64][65];
  const int bh = blockIdx.x >> 5, st = blockIdx.x & 31;
  const int tid = threadIdx.x;
  const float* src = V + ((size_t)bh * S_ + st * 64) * D_;
  for (int i = tid; i < 1024; i += 256) {
    int e = i * 4; int r = e >> 6; int c = e & 63;
    float4 v = *(const float4*)(src + e);
    T[r][c] = v.x; T[r][c + 1] = v.y; T[r][c + 2] = v.z; T[r][c + 3] = v.w;
  }
  __syncthreads();
  const int d = tid >> 2;
  const int sc = (tid & 3) * 16;
  unsigned short* dst = Vt + ((size_t)bh * D_ + d) * S_ + st * 64 + sc;
#pragma unroll
  for (int j = 0; j < 16; ++j) dst[j] = f2bf(T[sc + j][d]);
}

// ---------------- main kernel (barrier-free) ----------------
__global__ __launch_bounds__(256, 3)
void sdpa_main(const unsigned short* __restrict__ Qg, const unsigned short* __restrict__ Kg,
               const unsigned short* __restrict__ Vtg, float* __restrict__ Og,
               float* __restrict__ Pg) {
  // Only LDS: wave-private P tile transpose (fp32 acc layout -> bf16 A-frag).
  // Stride 72 shorts = 144B: bank-start 4*((m+quad)&7) -> uniform 8 lanes per
  // 4-bank group = LDS BW floor, no net conflict.
  __shared__ __align__(16) unsigned short Ps[64][72];

  const int tid = threadIdx.x;
  const int wave = tid >> 6;
  const int lane = tid & 63;
  const int m = lane & 15;
  const int quad = lane >> 4;

  const int bh = blockIdx.x & 31;
  // Balanced qb mapping: CU c gets blocks {c, c+256, c+512, c+768} ->
  // t in {u, u+8, u+16, u+24}. qb(t) below gives per-CU ktile sum
  // (17+g)+(32-g)+(16-g)+(1+g) = 66 for every CU; lightest round last.
  const int t = blockIdx.x >> 5;
  const int sg = t >> 3, g = t & 7;
  const int qb = (sg == 0) ? 16 + g : (sg == 1) ? 31 - g : (sg == 2) ? 15 - g : g;
  const int q0 = qb * 64;
  const int ktiles = qb + 1;

  const unsigned short* Kbh = Kg + (size_t)bh * S_ * D_;
  const unsigned short* Vbh = Vtg + (size_t)bh * D_ * S_;

  // Q fragments: one row per lane, resident in regs for the whole kernel.
  const unsigned short* Qrow = Qg + ((size_t)bh * S_ + q0 + wave * 16 + m) * D_;
  const short8 qf0 = *(const short8*)(Qrow + quad * 8);        // d 0..31 chunk
  const short8 qf1 = *(const short8*)(Qrow + 32 + quad * 8);   // d 32..63 chunk

  // ---- zero-fill masked attn region (streaming, non-temporal) ----
  {
    const int zc4 = (31 - qb) * 16;  // zero cols / 4
    if (zc4 > 0) {
      f32x4 z = {0.f, 0.f, 0.f, 0.f};
      float* base = Pg + ((size_t)(bh * S_ + q0 + wave * 16)) * S_ + (q0 + 64);
#pragma unroll 1
      for (int r = 0; r < 16; ++r)
        for (int i = lane; i < zc4; i += 64)
          __builtin_nontemporal_store(z, (f32x4*)(base + (size_t)r * S_ + i * 4));
    }
  }

  // K-tile fragment load: 8x 16B direct from L2 (K is L2-resident per XCD).
  auto loadK = [&](int kt, short8 (&kf)[4][2]) {
    const unsigned short* kb = Kbh + (size_t)kt * 64 * 64;
#pragma unroll
    for (int nt = 0; nt < 4; ++nt)
#pragma unroll
      for (int kc = 0; kc < 2; ++kc)
        kf[nt][kc] = *(const short8*)(kb + (nt * 16 + m) * 64 + (kc * 4 + quad) * 8);
  };

  // ================= pass A: row sums of exp(s) =================
  float lsum[4] = {0.f, 0.f, 0.f, 0.f};
  auto procA = [&](int kt, const short8 (&kf)[4][2]) {
    const bool diag = (kt == qb);
#pragma unroll
    for (int nt = 0; nt < 4; ++nt) {
      f32x4 acc = {0.f, 0.f, 0.f, 0.f};
      acc = __builtin_amdgcn_mfma_f32_16x16x32_bf16(qf0, kf[nt][0], acc, 0, 0, 0);
      acc = __builtin_amdgcn_mfma_f32_16x16x32_bf16(qf1, kf[nt][1], acc, 0, 0, 0);
      if (diag) {
        const int kg = kt * 64 + nt * 16 + m;
#pragma unroll
        for (int r = 0; r < 4; ++r) {
          const int qg = q0 + wave * 16 + quad * 4 + r;
          lsum[r] += (kg > qg) ? 0.f : __expf(acc[r] * 0.125f);
        }
      } else {
#pragma unroll
        for (int r = 0; r < 4; ++r) lsum[r] += __expf(acc[r] * 0.125f);
      }
    }
  };

  short8 kfA[4][2], kfB[4][2];
  loadK(0, kfA);
  for (int kt = 0; kt < ktiles; kt += 2) {
    if (kt + 1 < ktiles) {
      loadK(kt + 1, kfB);            // in flight under procA(kt)
      procA(kt, kfA);
      if (kt + 2 < ktiles) loadK(kt + 2, kfA);  // in flight under procA(kt+1)
      procA(kt + 1, kfB);
    } else {
      procA(kt, kfA);
    }
  }

  float invl[4];
#pragma unroll
  for (int r = 0; r < 4; ++r) {
    float v = lsum[r];
    v += __shfl_xor(v, 1); v += __shfl_xor(v, 2);
    v += __shfl_xor(v, 4); v += __shfl_xor(v, 8);
    invl[r] = 1.0f / v;
  }

  // ============ pass B: recompute S, write P, accumulate O ============
  f32x4 oacc[4];
#pragma unroll
  for (int dt = 0; dt < 4; ++dt) oacc[dt] = (f32x4){0.f, 0.f, 0.f, 0.f};

  loadK(0, kfA);
  for (int kt = 0; kt < ktiles; ++kt) {
    // V^T fragments: issue early -> latency hidden under QK^T + softmax.
    short8 vf[4][2];
#pragma unroll
    for (int dt = 0; dt < 4; ++dt)
#pragma unroll
      for (int kc = 0; kc < 2; ++kc)
        vf[dt][kc] = *(const short8*)(Vbh + (size_t)(dt * 16 + m) * S_ +
                                      kt * 64 + (kc * 4 + quad) * 8);

    const bool diag = (kt == qb);
#pragma unroll
    for (int nt = 0; nt < 4; ++nt) {
      f32x4 acc = {0.f, 0.f, 0.f, 0.f};
      acc = __builtin_amdgcn_mfma_f32_16x16x32_bf16(qf0, kfA[nt][0], acc, 0, 0, 0);
      acc = __builtin_amdgcn_mfma_f32_16x16x32_bf16(qf1, kfA[nt][1], acc, 0, 0, 0);
      const int kg = kt * 64 + nt * 16 + m;
#pragma unroll
      for (int r = 0; r < 4; ++r) {
        const int qg = q0 + wave * 16 + quad * 4 + r;
        float p = (diag && kg > qg) ? 0.f : __expf(acc[r] * 0.125f) * invl[r];
        __builtin_nontemporal_store(p, Pg + (size_t)(bh * S_ + qg) * S_ + kg);
        Ps[wave * 16 + quad * 4 + r][nt * 16 + m] = f2bf(p);
      }
    }

    if (kt + 1 < ktiles) loadK(kt + 1, kfA);  // in flight under PV MFMAs

    // PV: Ps is wave-private (each wave reads only the 16 rows it wrote);
    // compiler inserts the lgkmcnt wait for the ds_write->ds_read dep.
    const short8 pa0 = *(const short8*)&Ps[wave * 16 + m][quad * 8];
    const short8 pa1 = *(const short8*)&Ps[wave * 16 + m][32 + quad * 8];
#pragma unroll
    for (int dt = 0; dt < 4; ++dt) {
      oacc[dt] = __builtin_amdgcn_mfma_f32_16x16x32_bf16(pa0, vf[dt][0], oacc[dt], 0, 0, 0);
      oacc[dt] = __builtin_amdgcn_mfma_f32_16x16x32_bf16(pa1, vf[dt][1], oacc[dt], 0, 0, 0);
    }
  }

  // ---- write O tile ----
#pragma unroll
  for (int dt = 0; dt < 4; ++dt)
#pragma unroll
    for (int r = 0; r < 4; ++r)
      Og[(size_t)(bh * S_ + q0 + wave * 16 + quad * 4 + r) * D_ + dt * 16 + m] =
          oacc[dt][r];
}

extern "C" void kernel_launch(void* const* d_in, const int* in_sizes, int n_in,
                              void* d_out, int out_size, void* d_ws, size_t ws_size,
                              hipStream_t stream) {
  const float* Q = (const float*)d_in[0];
  const float* K = (const float*)d_in[1];
  const float* V = (const float*)d_in[2];
  float* Og = (float*)d_out;
  float* Pg = (float*)d_out + (size_t)BH_ * S_ * D_;

  unsigned short* Qbf = (unsigned short*)d_ws;                       // 8 MB
  unsigned short* Kbf = Qbf + (size_t)BH_ * S_ * D_;                 // 8 MB
  unsigned short* Vt  = Kbf + (size_t)BH_ * S_ * D_;                 // 8 MB

  const int n4 = (BH_ * S_ * D_) / 4;  // 1,048,576
  cvt_bf16<<<dim3(n4 / 256), dim3(256), 0, stream>>>(Q, Qbf, n4);
  cvt_bf16<<<dim3(n4 / 256), dim3(256), 0, stream>>>(K, Kbf, n4);
  vtrans<<<dim3(1024), dim3(256), 0, stream>>>(V, Vt);
  sdpa_main<<<dim3(1024), dim3(256), 0, stream>>>(Qbf, Kbf, Vt, Og, Pg);
}

// Round 3
// 666.548 us; speedup vs baseline: 1.0810x; 1.0810x over previous
//
#include <hip/hip_runtime.h>
#include <hip/hip_bf16.h>

// SDPA with materialized attention weights. B=2,H=16,S=2048,D=64, fp32 in/out.
// Outputs: O [B,H,S,D] then attn_weights [B,H,S,S] concatenated in d_out.
// Causal mask is structural (tril) -> k<=q, mask input unread.
//
// Round4: back to cooperative global_load_lds staging (R2's direct reg-loads
// regressed: 8x more load instrs + 4x redundant L2 traffic). Fix R0's actual
// defect: pass B had 2 barriers/ktile (fixed buffers). Now K AND V are
// double-buffered -> 1 barrier/ktile everywhere, stage(kt+1) issued right
// after the barrier so its vmcnt drain overlaps the whole compute(kt) phase.
// Q lives in registers (read once, proven R2). Ps is XOR-swizzled [64][64]
// (conflict-free b128 reads). LDS = 16+16+8 = 40 KB -> 4 blocks/CU.
// Balanced qb mapping: every CU's 4 resident blocks sum to 66 ktiles.
// Non-temporal stores for P / zero-fill keep L2 for K/V.

#define S_ 2048
#define D_ 64
#define BH_ 32

typedef short short8 __attribute__((ext_vector_type(8)));
typedef float f32x4 __attribute__((ext_vector_type(4)));
typedef unsigned short ushort4v __attribute__((ext_vector_type(4)));

__device__ __forceinline__ unsigned short f2bf(float f) {
  union { float f; unsigned u; } c; c.f = f;
  unsigned u = c.u + 0x7fffu + ((c.u >> 16) & 1u);  // RNE
  return (unsigned short)(u >> 16);
}

__device__ __forceinline__ void g2l16(const void* g, void* l) {
  __builtin_amdgcn_global_load_lds(
      (const __attribute__((address_space(1))) unsigned int*)g,
      (__attribute__((address_space(3))) unsigned int*)l, 16, 0, 0);
}

// ---------------- pre-kernels ----------------
__global__ __launch_bounds__(256) void cvt_bf16(const float* __restrict__ src,
                                                unsigned short* __restrict__ dst, int n4) {
  int i = blockIdx.x * 256 + threadIdx.x;
  if (i < n4) {
    float4 v = ((const float4*)src)[i];
    ushort4v u = { f2bf(v.x), f2bf(v.y), f2bf(v.z), f2bf(v.w) };
    ((ushort4v*)dst)[i] = u;
  }
}

// V [bh][s][d] fp32 -> Vt [bh][d][s] bf16
__global__ __launch_bounds__(256) void vtrans(const float* __restrict__ V,
                                              unsigned short* __restrict__ Vt) {
  __shared__ float T[64][65];
  const int bh = blockIdx.x >> 5, st = blockIdx.x & 31;
  const int tid = threadIdx.x;
  const float* src = V + ((size_t)bh * S_ + st * 64) * D_;
  for (int i = tid; i < 1024; i += 256) {
    int e = i * 4; int r = e >> 6; int c = e & 63;
    float4 v = *(const float4*)(src + e);
    T[r][c] = v.x; T[r][c + 1] = v.y; T[r][c + 2] = v.z; T[r][c + 3] = v.w;
  }
  __syncthreads();
  const int d = tid >> 2;
  const int sc = (tid & 3) * 16;
  unsigned short* dst = Vt + ((size_t)bh * D_ + d) * S_ + st * 64 + sc;
#pragma unroll
  for (int j = 0; j < 16; ++j) dst[j] = f2bf(T[sc + j][d]);
}

// ---------------- main kernel ----------------
__global__ __launch_bounds__(256, 4)
void sdpa_main(const unsigned short* __restrict__ Qg, const unsigned short* __restrict__ Kg,
               const unsigned short* __restrict__ Vtg, float* __restrict__ Og,
               float* __restrict__ Pg) {
  __shared__ __align__(16) unsigned short Kb2[2][64 * 64];  // 16 KB
  __shared__ __align__(16) unsigned short Vb2[2][64 * 64];  // 16 KB
  __shared__ __align__(16) unsigned short Ps[64 * 64];      // 8 KB, XOR-swizzled

  const int tid = threadIdx.x;
  const int wave = tid >> 6;
  const int lane = tid & 63;
  const int m = lane & 15;
  const int quad = lane >> 4;

  const int bh = blockIdx.x & 31;
  // Balanced qb mapping: CU c hosts blocks {c, c+256, c+512, c+768} ->
  // t in {u, u+8, u+16, u+24}; per-CU ktile sum = (17+g)+(32-g)+(16-g)+(1+g)=66.
  const int t = blockIdx.x >> 5;
  const int sg = t >> 3, g = t & 7;
  const int qb = (sg == 0) ? 16 + g : (sg == 1) ? 31 - g : (sg == 2) ? 15 - g : g;
  const int q0 = qb * 64;
  const int ktiles = qb + 1;

  const unsigned short* Kbh = Kg + (size_t)bh * S_ * D_;
  const unsigned short* Vbh = Vtg + (size_t)bh * D_ * S_;

  // Q fragments: one row per lane, resident in regs for the whole kernel.
  const unsigned short* Qrow = Qg + ((size_t)bh * S_ + q0 + wave * 16 + m) * D_;
  const short8 qf0 = *(const short8*)(Qrow + quad * 8);       // d 0..31 chunk
  const short8 qf1 = *(const short8*)(Qrow + 32 + quad * 8);  // d 32..63 chunk

  // cooperative stage of a 64x64 bf16 tile with XOR chunk swizzle (2 instrs/wave)
  auto stageK = [&](const unsigned short* gbase, unsigned short* lbase) {
#pragma unroll
    for (int j = 0; j < 2; ++j) {
      int gi = wave * 2 + j;
      int row = gi * 8 + (lane >> 3);
      int c = (lane & 7) ^ (row & 7);
      g2l16(gbase + row * 64 + c * 8, lbase + gi * 512);
    }
  };
  auto stageV = [&](int kt, unsigned short* lbase) {  // Vt rows have stride S_
#pragma unroll
    for (int j = 0; j < 2; ++j) {
      int gi = wave * 2 + j;
      int d = gi * 8 + (lane >> 3);
      int c = (lane & 7) ^ (d & 7);
      g2l16(Vbh + (size_t)d * S_ + kt * 64 + c * 8, lbase + gi * 512);
    }
  };
  // read one MFMA B fragment (8 bf16) from a swizzled staged tile
  auto frag = [&](const unsigned short* base, int row, int kc) -> short8 {
    int c = (kc * 4 + quad) ^ (row & 7);
    return *(const short8*)(base + row * 64 + c * 8);
  };

  // issue first K tile, then zero-fill masked attn region (streaming)
  stageK(Kbh, Kb2[0]);
  {
    const int zc4 = (31 - qb) * 16;  // zero cols / 4
    if (zc4 > 0) {
      f32x4 z = {0.f, 0.f, 0.f, 0.f};
      float* base = Pg + ((size_t)(bh * S_ + q0 + wave * 16)) * S_ + (q0 + 64);
#pragma unroll 1
      for (int r = 0; r < 16; ++r)
        for (int i = lane; i < zc4; i += 64)
          __builtin_nontemporal_store(z, (f32x4*)(base + (size_t)r * S_ + i * 4));
    }
  }

  // ================= pass A: row sums of exp(s) =================
  float lsum[4] = {0.f, 0.f, 0.f, 0.f};
  for (int kt = 0; kt < ktiles; ++kt) {
    __syncthreads();  // K[kt&1] ready (barrier drains vmcnt); prev compute done
    if (kt + 1 < ktiles) stageK(Kbh + (kt + 1) * 64 * 64, Kb2[(kt + 1) & 1]);
    const unsigned short* Kt = Kb2[kt & 1];
    const bool diag = (kt == qb);
#pragma unroll
    for (int nt = 0; nt < 4; ++nt) {
      f32x4 acc = {0.f, 0.f, 0.f, 0.f};
      acc = __builtin_amdgcn_mfma_f32_16x16x32_bf16(qf0, frag(Kt, nt * 16 + m, 0), acc, 0, 0, 0);
      acc = __builtin_amdgcn_mfma_f32_16x16x32_bf16(qf1, frag(Kt, nt * 16 + m, 1), acc, 0, 0, 0);
      if (diag) {
        const int kg = kt * 64 + nt * 16 + m;
#pragma unroll
        for (int r = 0; r < 4; ++r) {
          const int qg = q0 + wave * 16 + quad * 4 + r;
          lsum[r] += (kg > qg) ? 0.f : __expf(acc[r] * 0.125f);
        }
      } else {
#pragma unroll
        for (int r = 0; r < 4; ++r) lsum[r] += __expf(acc[r] * 0.125f);
      }
    }
  }

  // transition: all waves done reading Kb2, then issue pass-B tile 0 so the
  // loads fly during the invl reduction.
  __syncthreads();
  stageK(Kbh, Kb2[0]);
  stageV(0, Vb2[0]);

  float invl[4];
#pragma unroll
  for (int r = 0; r < 4; ++r) {
    float v = lsum[r];
    v += __shfl_xor(v, 1); v += __shfl_xor(v, 2);
    v += __shfl_xor(v, 4); v += __shfl_xor(v, 8);
    invl[r] = 1.0f / v;
  }

  // ============ pass B: recompute S, write P, accumulate O ============
  f32x4 oacc[4];
#pragma unroll
  for (int dt = 0; dt < 4; ++dt) oacc[dt] = (f32x4){0.f, 0.f, 0.f, 0.f};

  for (int kt = 0; kt < ktiles; ++kt) {
    __syncthreads();  // K/V[kt&1] ready; prev compute done -> other bufs free
    if (kt + 1 < ktiles) {
      stageK(Kbh + (kt + 1) * 64 * 64, Kb2[(kt + 1) & 1]);
      stageV(kt + 1, Vb2[(kt + 1) & 1]);
    }
    const unsigned short* Kt = Kb2[kt & 1];
    const unsigned short* Vt = Vb2[kt & 1];
    const bool diag = (kt == qb);
#pragma unroll
    for (int nt = 0; nt < 4; ++nt) {
      f32x4 acc = {0.f, 0.f, 0.f, 0.f};
      acc = __builtin_amdgcn_mfma_f32_16x16x32_bf16(qf0, frag(Kt, nt * 16 + m, 0), acc, 0, 0, 0);
      acc = __builtin_amdgcn_mfma_f32_16x16x32_bf16(qf1, frag(Kt, nt * 16 + m, 1), acc, 0, 0, 0);
      const int kg = kt * 64 + nt * 16 + m;
#pragma unroll
      for (int r = 0; r < 4; ++r) {
        const int qg = q0 + wave * 16 + quad * 4 + r;
        float p = (diag && kg > qg) ? 0.f : __expf(acc[r] * 0.125f) * invl[r];
        __builtin_nontemporal_store(p, Pg + (size_t)(bh * S_ + qg) * S_ + kg);
        const int prow = wave * 16 + quad * 4 + r;
        const int pcol = nt * 16 + m;
        // XOR-swizzled Ps: granule index ^= row&7 -> b128 reads conflict-free
        Ps[prow * 64 + (pcol & 7) + ((((pcol >> 3) ^ (prow & 7))) << 3)] = f2bf(p);
      }
    }
    // PV: Ps is wave-private (each wave reads only the 16 rows it wrote);
    // compiler inserts the lgkmcnt wait for the ds_write->ds_read dep.
#pragma unroll
    for (int dt = 0; dt < 4; ++dt)
#pragma unroll
      for (int kc = 0; kc < 2; ++kc) {
        const int prow = wave * 16 + m;
        short8 a = *(const short8*)&Ps[prow * 64 + (((kc * 4 + quad) ^ (prow & 7)) << 3)];
        short8 b = frag(Vt, dt * 16 + m, kc);
        oacc[dt] = __builtin_amdgcn_mfma_f32_16x16x32_bf16(a, b, oacc[dt], 0, 0, 0);
      }
  }

  // ---- write O tile ----
#pragma unroll
  for (int dt = 0; dt < 4; ++dt)
#pragma unroll
    for (int r = 0; r < 4; ++r)
      Og[(size_t)(bh * S_ + q0 + wave * 16 + quad * 4 + r) * D_ + dt * 16 + m] =
          oacc[dt][r];
}

extern "C" void kernel_launch(void* const* d_in, const int* in_sizes, int n_in,
                              void* d_out, int out_size, void* d_ws, size_t ws_size,
                              hipStream_t stream) {
  const float* Q = (const float*)d_in[0];
  const float* K = (const float*)d_in[1];
  const float* V = (const float*)d_in[2];
  float* Og = (float*)d_out;
  float* Pg = (float*)d_out + (size_t)BH_ * S_ * D_;

  unsigned short* Qbf = (unsigned short*)d_ws;                       // 8 MB
  unsigned short* Kbf = Qbf + (size_t)BH_ * S_ * D_;                 // 8 MB
  unsigned short* Vt  = Kbf + (size_t)BH_ * S_ * D_;                 // 8 MB

  const int n4 = (BH_ * S_ * D_) / 4;  // 1,048,576
  cvt_bf16<<<dim3(n4 / 256), dim3(256), 0, stream>>>(Q, Qbf, n4);
  cvt_bf16<<<dim3(n4 / 256), dim3(256), 0, stream>>>(K, Kbf, n4);
  vtrans<<<dim3(1024), dim3(256), 0, stream>>>(V, Vt);
  sdpa_main<<<dim3(1024), dim3(256), 0, stream>>>(Qbf, Kbf, Vt, Og, Pg);
}